// Round 7
// baseline (478.646 us; speedup 1.0000x reference)
//
#include <hip/hip_runtime.h>
#include <stdint.h>

#define BATCH 32768
#define NN    2500
#define NPAD  2560
#define DIM   256

#define BM 256
#define BN 256
#define MT_TOTAL (BATCH / BM)          // 128
#define NT_TOTAL (NPAD / BN)           // 10
#define TILES_PER_BLOCK 5
#define NBLOCKS ((MT_TOTAL * NT_TOTAL) / TILES_PER_BLOCK)   // 256

typedef __attribute__((ext_vector_type(8))) short short8;
typedef __attribute__((ext_vector_type(4))) float float4_;

__device__ __forceinline__ unsigned short f2bf(float f) {
  union { float f; uint32_t u; } v; v.f = f;
  uint32_t u = v.u;
  return (unsigned short)((u + 0x7FFFu + ((u >> 16) & 1u)) >> 16);
}

__device__ __forceinline__ void gload_lds16(const void* g, void* lds) {
  __builtin_amdgcn_global_load_lds(
      (const __attribute__((address_space(1))) unsigned int*)g,
      (__attribute__((address_space(3))) unsigned int*)lds, 16, 0, 0);
}

// ---------------- prep: fp32 -> bf16 copy + exact fp32 row norm ----------------
__global__ void prep_rows2(const float* __restrict__ xin, const float* __restrict__ win_,
                           unsigned short* __restrict__ outb, float* __restrict__ sq) {
  int row  = blockIdx.x * 4 + (threadIdx.x >> 6);
  int lane = threadIdx.x & 63;
  float4 v = make_float4(0.f, 0.f, 0.f, 0.f);
  if (row < BATCH) {
    v = ((const float4*)(xin + (size_t)row * DIM))[lane];
  } else if (row - BATCH < NN) {
    v = ((const float4*)(win_ + (size_t)(row - BATCH) * DIM))[lane];
  }
  float s = v.x * v.x + v.y * v.y + v.z * v.z + v.w * v.w;
  *(ushort4*)(outb + (size_t)row * DIM + lane * 4) =
      make_ushort4(f2bf(v.x), f2bf(v.y), f2bf(v.z), f2bf(v.w));
  for (int off = 32; off > 0; off >>= 1) s += __shfl_down(s, off, 64);
  if (lane == 0) sq[row] = s;
}

// ---------------- main GEMM: persistent-B blocks, 256x256 tiles, swapped MFMA ----------------
// Structure: 256 blocks (1/CU). Tiles nt-major (t = nt*128 + mt); block b owns
// t in [5b, 5b+5) -> 5 M-tiles at (almost always) fixed n0. B panel (256x256
// bf16 = 128 KB LDS) staged ONCE per block (9/256 blocks restage at an nt
// boundary). Between M-tiles: NO barriers — tile k's float4 stores (fire-and-
// forget) overlap tile k+1's A-loads and K-loop. This removes r4's per-round
// serialized write drain AND r6's doubled read traffic (B stage total: 32 MB).
// K-loop: barrier-free; A fragments global->reg (L2/L3-hot); B ds_read_b128
// via verified XOR swizzle (phys chunk pc of row r holds logical pc^(r&7);
// read slot (ks*4+q)^(i&7) -> conflict-free; r2/r4 measured 0 conflicts).
// SWAPPED mfma(b,a): lane(q,i) reg r = cross[m=..+ti*16+i][n=..+tj*16+q*4+r]
// -> 4 consecutive n per lane -> global_store_dwordx4 (aligned: NN*4%16==0).
__global__ __launch_bounds__(512, 2)
void cdist_gemm_bf16(const unsigned short* __restrict__ Xb,
                     const unsigned short* __restrict__ Wb,
                     const float* __restrict__ xsq, const float* __restrict__ wsq,
                     float* __restrict__ out) {
  __shared__ __align__(16) unsigned short Bs[BN * DIM];   // 128 KB

  const int tid  = threadIdx.x;
  const int lane = tid & 63;
  const int wave = tid >> 6;                 // 0..7

  const int wr = wave >> 1;                  // 0..3  (64-row slice of M)
  const int wc = wave & 1;                   // 0..1  (128-col slice of N)
  const int q  = lane >> 4;                  // k-chunk 0..3
  const int i  = lane & 15;

  const int t0 = blockIdx.x * TILES_PER_BLOCK;
  int cur_nt = -1;

  for (int tt = 0; tt < TILES_PER_BLOCK; ++tt) {
    const int t  = t0 + tt;
    const int nt = t >> 7;                   // t / MT_TOTAL
    const int mt = t & (MT_TOTAL - 1);
    const int m0 = mt * BM;
    const int n0 = nt * BN;

    if (nt != cur_nt) {
      if (tt != 0) __syncthreads();          // all waves done reading old B
      // stage whole B panel: 8192 16B chunks, linear LDS dest,
      // pre-swizzled global source (chunk lc = pc ^ (row&7))
#pragma unroll
      for (int j = 0; j < 16; ++j) {
        int c   = j * 512 + tid;             // chunk id 0..8191
        int row = c >> 5;                    // 32 chunks per 512B row
        int pc  = c & 31;
        int lc  = pc ^ (row & 7);
        gload_lds16(Wb + (size_t)(n0 + row) * DIM + lc * 8, &Bs[c * 8]);
      }
      __syncthreads();                       // stage drain: once per block (mostly)
      cur_nt = nt;
    }

    // per-lane A base: rows (m0 + wr*64 + ti*16 + i), k-chunk q
    const unsigned short* gA = Xb + (size_t)(m0 + wr * 64 + i) * DIM + q * 8;

    float4_ acc[4][8] = {};

#pragma unroll
    for (int ks = 0; ks < 8; ++ks) {
      short8 a[4], b[8];
#pragma unroll
      for (int tA = 0; tA < 4; ++tA)
        a[tA] = *(const short8*)(gA + (size_t)(tA * 16) * DIM + ks * 32);
#pragma unroll
      for (int tj = 0; tj < 8; ++tj) {
        int row = wc * 128 + tj * 16 + i;
        int pc  = (ks * 4 + q) ^ (i & 7);
        b[tj] = *(const short8*)&Bs[(row << 8) + (pc << 3)];
      }
      // SWAPPED operands: first operand supplies C's row index -> n side.
#pragma unroll
      for (int ti = 0; ti < 4; ++ti)
#pragma unroll
        for (int tj = 0; tj < 8; ++tj)
          acc[ti][tj] = __builtin_amdgcn_mfma_f32_16x16x32_bf16(
              b[tj], a[ti], acc[ti][tj], 0, 0, 0);
    }

    // epilogue: d = sqrt(max(xsq + wsq - 2*cross, 0)); no barrier — stores
    // overlap the next M-tile's loads/MFMA.
#pragma unroll
    for (int ti = 0; ti < 4; ++ti) {
      const int m  = m0 + wr * 64 + ti * 16 + i;
      const float xm = xsq[m];
      float* orow = out + (size_t)m * NN;
#pragma unroll
      for (int tj = 0; tj < 8; ++tj) {
        int nb = n0 + wc * 128 + tj * 16 + q * 4;
        if (nb < NN) {                       // NN % 4 == 0: quad all-or-nothing
          float4 wv = *(const float4*)&wsq[nb];
          float4 o;
          o.x = sqrtf(fmaxf(xm + wv.x - 2.0f * acc[ti][tj][0], 0.f));
          o.y = sqrtf(fmaxf(xm + wv.y - 2.0f * acc[ti][tj][1], 0.f));
          o.z = sqrtf(fmaxf(xm + wv.z - 2.0f * acc[ti][tj][2], 0.f));
          o.w = sqrtf(fmaxf(xm + wv.w - 2.0f * acc[ti][tj][3], 0.f));
          *(float4*)&orow[nb] = o;
        }
      }
    }
  }
}

// ---------------- fallback path (ws too small): round-1 kernels ----------------
#define LDA 72
#define BKF 64
#define BMF 128
#define BNF 128
__global__ void row_sq_norm(const float* __restrict__ in, float* __restrict__ out,
                            int nrows, int nvalid) {
  int row  = blockIdx.x * 4 + (threadIdx.x >> 6);
  int lane = threadIdx.x & 63;
  if (row >= nrows) return;
  float s = 0.f;
  if (row < nvalid) {
    float4 v = ((const float4*)(in + (size_t)row * DIM))[lane];
    s = v.x * v.x + v.y * v.y + v.z * v.z + v.w * v.w;
  }
  for (int off = 32; off > 0; off >>= 1) s += __shfl_down(s, off, 64);
  if (lane == 0) out[row] = s;
}

__global__ __launch_bounds__(256, 2)
void cdist_gemm_f32(const float* __restrict__ X, const float* __restrict__ W,
                    const float* __restrict__ xsq, const float* __restrict__ wsq,
                    float* __restrict__ out) {
  __shared__ __align__(16) unsigned short As[BMF * LDA];
  __shared__ __align__(16) unsigned short Bs2[BNF * LDA];
  const int tid = threadIdx.x, lane = tid & 63, wave = tid >> 6;
  const int m0 = blockIdx.x * BMF, n0 = blockIdx.y * BNF;
  const int wr = wave >> 1, wc = wave & 1;
  float4_ acc[4][4] = {};
  const int s_col4 = tid & 15, s_row0 = tid >> 4;
  for (int kc = 0; kc < DIM; kc += BKF) {
#pragma unroll
    for (int j = 0; j < 8; ++j) {
      int r = s_row0 + 16 * j;
      float4 v = *(const float4*)(X + (size_t)(m0 + r) * DIM + kc + s_col4 * 4);
      *(ushort4*)&As[r * LDA + s_col4 * 4] =
          make_ushort4(f2bf(v.x), f2bf(v.y), f2bf(v.z), f2bf(v.w));
    }
#pragma unroll
    for (int j = 0; j < 8; ++j) {
      int r = s_row0 + 16 * j, n = n0 + r;
      float4 v = make_float4(0.f, 0.f, 0.f, 0.f);
      if (n < NN) v = *(const float4*)(W + (size_t)n * DIM + kc + s_col4 * 4);
      *(ushort4*)&Bs2[r * LDA + s_col4 * 4] =
          make_ushort4(f2bf(v.x), f2bf(v.y), f2bf(v.z), f2bf(v.w));
    }
    __syncthreads();
    const int q = lane >> 4, i = lane & 15;
#pragma unroll
    for (int ks = 0; ks < BKF; ks += 32) {
      short8 a[4], b[4];
#pragma unroll
      for (int t = 0; t < 4; ++t) {
        a[t] = *(const short8*)&As[(wr * 64 + t * 16 + i) * LDA + ks + q * 8];
        b[t] = *(const short8*)&Bs2[(wc * 64 + t * 16 + i) * LDA + ks + q * 8];
      }
#pragma unroll
      for (int ti = 0; ti < 4; ++ti)
#pragma unroll
        for (int tj = 0; tj < 4; ++tj)
          acc[ti][tj] = __builtin_amdgcn_mfma_f32_16x16x32_bf16(
              a[ti], b[tj], acc[ti][tj], 0, 0, 0);
    }
    __syncthreads();
  }
  const int q = lane >> 4, i = lane & 15;
#pragma unroll
  for (int ti = 0; ti < 4; ++ti) {
    int grow_base = m0 + wr * 64 + ti * 16 + q * 4;
#pragma unroll
    for (int tj = 0; tj < 4; ++tj) {
      int gcol = n0 + wc * 64 + tj * 16 + i;
      if (gcol < NN) {
        float wn = wsq[gcol];
#pragma unroll
        for (int r = 0; r < 4; ++r) {
          int grow = grow_base + r;
          float d2 = xsq[grow] + wn - 2.0f * acc[ti][tj][r];
          out[(size_t)grow * NN + gcol] = sqrtf(fmaxf(d2, 0.f));
        }
      }
    }
  }
}

extern "C" void kernel_launch(void* const* d_in, const int* in_sizes, int n_in,
                              void* d_out, int out_size, void* d_ws, size_t ws_size,
                              hipStream_t stream) {
  const float* x = (const float*)d_in[0];
  const float* w = (const float*)d_in[1];

  const size_t xb_elems = (size_t)BATCH * DIM;          // bf16
  const size_t wb_elems = (size_t)NPAD * DIM;           // bf16
  const size_t need = xb_elems * 2 + wb_elems * 2 + (size_t)BATCH * 4 + (size_t)NPAD * 4;

  if (ws_size >= need) {
    unsigned short* Xb = (unsigned short*)d_ws;
    unsigned short* Wb = Xb + xb_elems;
    float* xsq = (float*)(Wb + wb_elems);
    float* wsq = xsq + BATCH;

    prep_rows2<<<(BATCH + NPAD) / 4, 256, 0, stream>>>(x, w, Xb, xsq);

    cdist_gemm_bf16<<<dim3(NBLOCKS), 512, 0, stream>>>(
        Xb, Wb, xsq, wsq, (float*)d_out);
  } else {
    float* xsq = (float*)d_ws;
    float* wsq = xsq + BATCH;
    row_sq_norm<<<BATCH / 4, 256, 0, stream>>>(x, xsq, BATCH, BATCH);
    row_sq_norm<<<NPAD / 4, 256, 0, stream>>>(w, wsq, NPAD, NN);
    dim3 grid(BATCH / BMF, NPAD / BNF);
    cdist_gemm_f32<<<grid, 256, 0, stream>>>(x, w, xsq, wsq, (float*)d_out);
  }
}

// Round 8
// 451.762 us; speedup vs baseline: 1.0595x; 1.0595x over previous
//
#include <hip/hip_runtime.h>
#include <stdint.h>

#define BATCH 32768
#define NN    2500
#define NPAD  2560
#define DIM   256

#define BM 256
#define BN 128
#define NBLOCKS ((BATCH / BM) * (NPAD / BN))   // 128 * 20 = 2560

typedef __attribute__((ext_vector_type(8))) short short8;
typedef __attribute__((ext_vector_type(4))) float float4_;

__device__ __forceinline__ unsigned short f2bf(float f) {
  union { float f; uint32_t u; } v; v.f = f;
  uint32_t u = v.u;
  return (unsigned short)((u + 0x7FFFu + ((u >> 16) & 1u)) >> 16);
}

__device__ __forceinline__ void gload_lds16(const void* g, void* lds) {
  __builtin_amdgcn_global_load_lds(
      (const __attribute__((address_space(1))) unsigned int*)g,
      (__attribute__((address_space(3))) unsigned int*)lds, 16, 0, 0);
}

// ---------------- prep: fp32 -> bf16 copy + exact fp32 row norm ----------------
__global__ void prep_rows2(const float* __restrict__ xin, const float* __restrict__ win_,
                           unsigned short* __restrict__ outb, float* __restrict__ sq) {
  int row  = blockIdx.x * 4 + (threadIdx.x >> 6);
  int lane = threadIdx.x & 63;
  float4 v = make_float4(0.f, 0.f, 0.f, 0.f);
  if (row < BATCH) {
    v = ((const float4*)(xin + (size_t)row * DIM))[lane];
  } else if (row - BATCH < NN) {
    v = ((const float4*)(win_ + (size_t)(row - BATCH) * DIM))[lane];
  }
  float s = v.x * v.x + v.y * v.y + v.z * v.z + v.w * v.w;
  *(ushort4*)(outb + (size_t)row * DIM + lane * 4) =
      make_ushort4(f2bf(v.x), f2bf(v.y), f2bf(v.z), f2bf(v.w));
  for (int off = 32; off > 0; off >>= 1) s += __shfl_down(s, off, 64);
  if (lane == 0) sq[row] = s;
}

// ---------------- main GEMM: 256x128 tile, LDS-bounced row-contiguous epilogue ----------------
// Diagnosis (r0-r7 ledger): write stream (390 MB) runs at ~1.4-2.5 TB/s because
// every store covers only 64-B segments scattered over rows 10 KB apart (poor
// HBM page locality). Fill kernels hit 5.5 TB/s on the same buffer. Writes ARE
// the kernel (156 us of r4's ~156 us gemm).
// Fix: keep the proven K-loop (B panel in LDS staged once, barrier-free body,
// swapped mfma(b,a)); after K-loop Bs is dead -> reuse as a 128-row f32 d-value
// buffer. Waves write finished d's via swizzled f4 LDS writes; then ALL waves
// stream rows out as dense 512-B row bursts (one dwordx4 instr = 2 full rows).
// 2 phases of 128 rows. 256 thr / 4 waves, 64 KB LDS -> 2 blocks/CU so
// barriers + the phase-0 store drain overlap with the co-resident block.
__global__ __launch_bounds__(256, 2)
void cdist_gemm_bf16(const unsigned short* __restrict__ Xb,
                     const unsigned short* __restrict__ Wb,
                     const float* __restrict__ xsq, const float* __restrict__ wsq,
                     float* __restrict__ out) {
  __shared__ __align__(16) unsigned short Bs[BN * DIM];   // 64 KB
  float* BsF = (float*)Bs;                                // epilogue alias

  const int tid  = threadIdx.x;
  const int lane = tid & 63;
  const int wave = tid >> 6;                 // 0..3, wave = 64 m-rows x 128 n-cols

  // XCD-chunked mapping: 2560 blocks = 8 XCDs x 320; per XCD 16 M-tiles x 20
  // N-tiles, N inner -> per-XCD set = X slice (2 MB) + W (1.31 MB) < 4 MB L2.
  const int bid = blockIdx.x;
  const int loc = bid >> 3;                  // 0..319
  const int mt  = (bid & 7) * 16 + loc / 20; // 0..127
  const int nt  = loc % 20;                  // 0..19
  const int m0  = mt * BM;
  const int n0  = nt * BN;

  const int q = lane >> 4;                   // k-chunk 0..3
  const int i = lane & 15;

  // ---- stage whole B panel once: 4096 16B chunks, linear LDS dest,
  //      pre-swizzled global source (chunk lc = pc ^ (row&7)) ----
#pragma unroll
  for (int j = 0; j < 16; ++j) {
    int c   = j * 256 + tid;                 // chunk id 0..4095
    int row = c >> 5;                        // 32 chunks per 512B row
    int pc  = c & 31;
    int lc  = pc ^ (row & 7);
    gload_lds16(Wb + (size_t)(n0 + row) * DIM + lc * 8, &Bs[c * 8]);
  }

  // per-lane A base: rows (m0 + wave*64 + ti*16 + i), k-chunk q
  const unsigned short* gA = Xb + (size_t)(m0 + wave * 64 + i) * DIM + q * 8;

  float4_ acc[4][8] = {};

  __syncthreads();   // B panel resident

#pragma unroll
  for (int ks = 0; ks < 8; ++ks) {
    short8 a[4], b[8];
#pragma unroll
    for (int t = 0; t < 4; ++t)
      a[t] = *(const short8*)(gA + (size_t)(t * 16) * DIM + ks * 32);
#pragma unroll
    for (int tj = 0; tj < 8; ++tj) {
      int row = tj * 16 + i;
      int pc  = (ks * 4 + q) ^ (i & 7);
      b[tj] = *(const short8*)&Bs[(row << 8) + (pc << 3)];
    }
    // SWAPPED operands: first operand supplies C's row index -> n side.
    // lane(q,i) reg r = cross[m = m0+wave*64+ti*16+i][n = n0+tj*16+q*4+r]
#pragma unroll
    for (int ti = 0; ti < 4; ++ti)
#pragma unroll
      for (int tj = 0; tj < 8; ++tj)
        acc[ti][tj] = __builtin_amdgcn_mfma_f32_16x16x32_bf16(
            b[tj], a[ti], acc[ti][tj], 0, 0, 0);
  }

  __syncthreads();   // all b-reads done; Bs becomes the epilogue buffer

  // epilogue: two phases of 128 m-rows. Phase writers = waves {2p, 2p+1}.
  // LDS layout: row lr (0..127) x 128 f32 (512 B, 32 16-B slots), slot
  // swizzle phys = slot ^ (lr&7) -> writes <=2-way, reads dense.
#pragma unroll
  for (int p = 0; p < 2; ++p) {
    if ((wave >> 1) == p) {
      const int k = wave & 1;
#pragma unroll
      for (int ti = 0; ti < 4; ++ti) {
        const int lr = k * 64 + ti * 16 + i;          // local row 0..127
        const int m  = m0 + p * 128 + lr;
        const float xm = xsq[m];
#pragma unroll
        for (int tj = 0; tj < 8; ++tj) {
          const int nl = tj * 16 + q * 4;             // local col 0..124
          float4 wv = *(const float4*)&wsq[n0 + nl];
          float4_ o;
          o[0] = sqrtf(fmaxf(xm + wv.x - 2.0f * acc[ti][tj][0], 0.f));
          o[1] = sqrtf(fmaxf(xm + wv.y - 2.0f * acc[ti][tj][1], 0.f));
          o[2] = sqrtf(fmaxf(xm + wv.z - 2.0f * acc[ti][tj][2], 0.f));
          o[3] = sqrtf(fmaxf(xm + wv.w - 2.0f * acc[ti][tj][3], 0.f));
          const int slot = (tj * 4 + q) ^ (lr & 7);
          *(float4_*)&BsF[lr * 128 + slot * 4] = o;
        }
      }
    }
    __syncthreads();
    // all 4 waves stream out: wave w owns local rows [w*32, w*32+32),
    // one dwordx4 instr covers 2 full 512-B rows (lanes 0-31 row, 32-63 row+1).
    {
      const int half = lane >> 5;                     // 0/1
      const int sl   = lane & 31;                     // slot in row
#pragma unroll
      for (int jj = 0; jj < 16; ++jj) {
        const int lr = wave * 32 + jj * 2 + half;
        const int phys = sl ^ (lr & 7);
        float4_ v = *(const float4_*)&BsF[lr * 128 + phys * 4];
        const int nb = n0 + sl * 4;
        if (nb < NN)                                  // NN%4==0: quad-exact
          *(float4_*)&out[(size_t)(m0 + p * 128 + lr) * NN + nb] = v;
      }
    }
    if (p == 0) __syncthreads();   // phase-0 reads done before phase-1 writes
  }
}

// ---------------- fallback path (ws too small): round-1 kernels ----------------
#define LDA 72
#define BKF 64
#define BMF 128
#define BNF 128
__global__ void row_sq_norm(const float* __restrict__ in, float* __restrict__ out,
                            int nrows, int nvalid) {
  int row  = blockIdx.x * 4 + (threadIdx.x >> 6);
  int lane = threadIdx.x & 63;
  if (row >= nrows) return;
  float s = 0.f;
  if (row < nvalid) {
    float4 v = ((const float4*)(in + (size_t)row * DIM))[lane];
    s = v.x * v.x + v.y * v.y + v.z * v.z + v.w * v.w;
  }
  for (int off = 32; off > 0; off >>= 1) s += __shfl_down(s, off, 64);
  if (lane == 0) out[row] = s;
}

__global__ __launch_bounds__(256, 2)
void cdist_gemm_f32(const float* __restrict__ X, const float* __restrict__ W,
                    const float* __restrict__ xsq, const float* __restrict__ wsq,
                    float* __restrict__ out) {
  __shared__ __align__(16) unsigned short As[BMF * LDA];
  __shared__ __align__(16) unsigned short Bs2[BNF * LDA];
  const int tid = threadIdx.x, lane = tid & 63, wave = tid >> 6;
  const int m0 = blockIdx.x * BMF, n0 = blockIdx.y * BNF;
  const int wr = wave >> 1, wc = wave & 1;
  float4_ acc[4][4] = {};
  const int s_col4 = tid & 15, s_row0 = tid >> 4;
  for (int kc = 0; kc < DIM; kc += BKF) {
#pragma unroll
    for (int j = 0; j < 8; ++j) {
      int r = s_row0 + 16 * j;
      float4 v = *(const float4*)(X + (size_t)(m0 + r) * DIM + kc + s_col4 * 4);
      *(ushort4*)&As[r * LDA + s_col4 * 4] =
          make_ushort4(f2bf(v.x), f2bf(v.y), f2bf(v.z), f2bf(v.w));
    }
#pragma unroll
    for (int j = 0; j < 8; ++j) {
      int r = s_row0 + 16 * j, n = n0 + r;
      float4 v = make_float4(0.f, 0.f, 0.f, 0.f);
      if (n < NN) v = *(const float4*)(W + (size_t)n * DIM + kc + s_col4 * 4);
      *(ushort4*)&Bs2[r * LDA + s_col4 * 4] =
          make_ushort4(f2bf(v.x), f2bf(v.y), f2bf(v.z), f2bf(v.w));
    }
    __syncthreads();
    const int q = lane >> 4, i = lane & 15;
#pragma unroll
    for (int ks = 0; ks < BKF; ks += 32) {
      short8 a[4], b[4];
#pragma unroll
      for (int t = 0; t < 4; ++t) {
        a[t] = *(const short8*)&As[(wr * 64 + t * 16 + i) * LDA + ks + q * 8];
        b[t] = *(const short8*)&Bs2[(wc * 64 + t * 16 + i) * LDA + ks + q * 8];
      }
#pragma unroll
      for (int ti = 0; ti < 4; ++ti)
#pragma unroll
        for (int tj = 0; tj < 4; ++tj)
          acc[ti][tj] = __builtin_amdgcn_mfma_f32_16x16x32_bf16(
              a[ti], b[tj], acc[ti][tj], 0, 0, 0);
    }
    __syncthreads();
  }
  const int q = lane >> 4, i = lane & 15;
#pragma unroll
  for (int ti = 0; ti < 4; ++ti) {
    int grow_base = m0 + wr * 64 + ti * 16 + q * 4;
#pragma unroll
    for (int tj = 0; tj < 4; ++tj) {
      int gcol = n0 + wc * 64 + tj * 16 + i;
      if (gcol < NN) {
        float wn = wsq[gcol];
#pragma unroll
        for (int r = 0; r < 4; ++r) {
          int grow = grow_base + r;
          float d2 = xsq[grow] + wn - 2.0f * acc[ti][tj][r];
          out[(size_t)grow * NN + gcol] = sqrtf(fmaxf(d2, 0.f));
        }
      }
    }
  }
}

extern "C" void kernel_launch(void* const* d_in, const int* in_sizes, int n_in,
                              void* d_out, int out_size, void* d_ws, size_t ws_size,
                              hipStream_t stream) {
  const float* x = (const float*)d_in[0];
  const float* w = (const float*)d_in[1];

  const size_t xb_elems = (size_t)BATCH * DIM;          // bf16
  const size_t wb_elems = (size_t)NPAD * DIM;           // bf16
  const size_t need = xb_elems * 2 + wb_elems * 2 + (size_t)BATCH * 4 + (size_t)NPAD * 4;

  if (ws_size >= need) {
    unsigned short* Xb = (unsigned short*)d_ws;
    unsigned short* Wb = Xb + xb_elems;
    float* xsq = (float*)(Wb + wb_elems);
    float* wsq = xsq + BATCH;

    prep_rows2<<<(BATCH + NPAD) / 4, 256, 0, stream>>>(x, w, Xb, xsq);

    cdist_gemm_bf16<<<dim3(NBLOCKS), 256, 0, stream>>>(
        Xb, Wb, xsq, wsq, (float*)d_out);
  } else {
    float* xsq = (float*)d_ws;
    float* wsq = xsq + BATCH;
    row_sq_norm<<<BATCH / 4, 256, 0, stream>>>(x, xsq, BATCH, BATCH);
    row_sq_norm<<<NPAD / 4, 256, 0, stream>>>(w, wsq, NPAD, NN);
    dim3 grid(BATCH / BMF, NPAD / BNF);
    cdist_gemm_f32<<<grid, 256, 0, stream>>>(x, w, xsq, wsq, (float*)d_out);
  }
}

// Round 9
// 440.640 us; speedup vs baseline: 1.0863x; 1.0252x over previous
//
#include <hip/hip_runtime.h>
#include <stdint.h>

#define BATCH 32768
#define NN    2500
#define NPAD  2560
#define DIM   256

#define BM 256
#define BN 256

typedef __attribute__((ext_vector_type(8))) short short8;
typedef __attribute__((ext_vector_type(4))) float float4_;

__device__ __forceinline__ unsigned short f2bf(float f) {
  union { float f; uint32_t u; } v; v.f = f;
  uint32_t u = v.u;
  return (unsigned short)((u + 0x7FFFu + ((u >> 16) & 1u)) >> 16);
}

__device__ __forceinline__ void gload_lds16(const void* g, void* lds) {
  __builtin_amdgcn_global_load_lds(
      (const __attribute__((address_space(1))) unsigned int*)g,
      (__attribute__((address_space(3))) unsigned int*)lds, 16, 0, 0);
}

// ---------------- prep: fp32 -> bf16 copy + exact fp32 row norm ----------------
__global__ void prep_rows2(const float* __restrict__ xin, const float* __restrict__ win_,
                           unsigned short* __restrict__ outb, float* __restrict__ sq) {
  int row  = blockIdx.x * 4 + (threadIdx.x >> 6);
  int lane = threadIdx.x & 63;
  float4 v = make_float4(0.f, 0.f, 0.f, 0.f);
  if (row < BATCH) {
    v = ((const float4*)(xin + (size_t)row * DIM))[lane];
  } else if (row - BATCH < NN) {
    v = ((const float4*)(win_ + (size_t)(row - BATCH) * DIM))[lane];
  }
  float s = v.x * v.x + v.y * v.y + v.z * v.z + v.w * v.w;
  *(ushort4*)(outb + (size_t)row * DIM + lane * 4) =
      make_ushort4(f2bf(v.x), f2bf(v.y), f2bf(v.z), f2bf(v.w));
  for (int off = 32; off > 0; off >>= 1) s += __shfl_down(s, off, 64);
  if (lane == 0) sq[row] = s;
}

// ---------------- main GEMM: r4 structure + swapped-operand MFMA f4 epilogue ----------------
// r4 (best, gemm ~158us): 256x256 tile, B panel (128 KB) staged to LDS once,
// single barrier, barrier-free K-loop with A global->reg. This round changes
// ONE thing vs r4: mfma operand order swapped (b, a) so lane(q,i) reg r holds
// cross[m = m0+wr*64+ti*16+i][n = n0+wc*128+tj*16+q*4+r] -> 4 consecutive n
// per lane -> epilogue is 32 global_store_dwordx4/thread (was 128 scalar
// stores): 4x fewer store instrs, 1 KB contiguous footprint per wave-instr
// (16 rows x 64 B) instead of 256 B. Isolates the store path at fixed reads.
// Swizzle unchanged (verified 0 conflicts): phys chunk pc of row r holds
// logical pc^(r&7); read slot (ks*4+q)^(i&7).
__global__ __launch_bounds__(512, 2)
void cdist_gemm_bf16(const unsigned short* __restrict__ Xb,
                     const unsigned short* __restrict__ Wb,
                     const float* __restrict__ xsq, const float* __restrict__ wsq,
                     float* __restrict__ out) {
  __shared__ __align__(16) unsigned short Bs[BN * DIM];   // 128 KB

  const int tid  = threadIdx.x;
  const int lane = tid & 63;
  const int wave = tid >> 6;                 // 0..7

  // XCD-chunked mapping: 1280 blocks = 8 XCDs x 160; per XCD 16 M-tiles x 10
  // N-tiles, N inner -> per-XCD set = X slice (2 MB) + W (1.31 MB) < 4 MB L2.
  const int bid = blockIdx.x;
  const int loc = bid >> 3;                  // 0..159
  const int mt  = (bid & 7) * 16 + loc / 10; // 0..127
  const int nt  = loc % 10;                  // 0..9
  const int m0  = mt * BM;
  const int n0  = nt * BN;

  const int wr = wave >> 1;                  // 0..3  (64-row slice of M)
  const int wc = wave & 1;                   // 0..1  (128-col slice of N)
  const int q  = lane >> 4;                  // k-chunk 0..3
  const int i  = lane & 15;

  // ---- stage whole B panel once: 8192 16B chunks, linear LDS dest,
  //      pre-swizzled global source (chunk lc = pc ^ (row&7)) ----
#pragma unroll
  for (int j = 0; j < 16; ++j) {
    int c   = j * 512 + tid;                 // chunk id 0..8191
    int row = c >> 5;                        // 32 chunks per 512B row
    int pc  = c & 31;
    int lc  = pc ^ (row & 7);
    gload_lds16(Wb + (size_t)(n0 + row) * DIM + lc * 8, &Bs[c * 8]);
  }

  // per-lane A base: rows (m0 + wr*64 + ti*16 + i), k-chunk q
  const unsigned short* gA = Xb + (size_t)(m0 + wr * 64 + i) * DIM + q * 8;

  float4_ acc[4][8] = {};

  __syncthreads();   // the ONLY barrier: B panel resident from here on

#pragma unroll
  for (int ks = 0; ks < 8; ++ks) {
    short8 a[4], b[8];
#pragma unroll
    for (int t = 0; t < 4; ++t)
      a[t] = *(const short8*)(gA + (size_t)(t * 16) * DIM + ks * 32);
#pragma unroll
    for (int tj = 0; tj < 8; ++tj) {
      int row = wc * 128 + tj * 16 + i;
      int pc  = (ks * 4 + q) ^ (i & 7);
      b[tj] = *(const short8*)&Bs[(row << 8) + (pc << 3)];
    }
    // SWAPPED operands: first operand supplies the n side of C.
#pragma unroll
    for (int ti = 0; ti < 4; ++ti)
#pragma unroll
      for (int tj = 0; tj < 8; ++tj)
        acc[ti][tj] = __builtin_amdgcn_mfma_f32_16x16x32_bf16(
            b[tj], a[ti], acc[ti][tj], 0, 0, 0);
  }

  // epilogue: d = sqrt(max(xsq + wsq - 2*cross, 0))
  // swapped C/D: lane(q,i) reg r = cross[m0+wr*64+ti*16+i][n0+wc*128+tj*16+q*4+r]
  // -> one float4 store per acc tile (16B contiguous & aligned: NN*4%16==0).
#pragma unroll
  for (int ti = 0; ti < 4; ++ti) {
    const int m  = m0 + wr * 64 + ti * 16 + i;
    const float xm = xsq[m];
    float* orow = out + (size_t)m * NN;
#pragma unroll
    for (int tj = 0; tj < 8; ++tj) {
      int nb = n0 + wc * 128 + tj * 16 + q * 4;
      if (nb < NN) {                          // NN % 4 == 0: quad all-or-nothing
        float4 wv = *(const float4*)&wsq[nb];
        float4 o;
        o.x = sqrtf(fmaxf(xm + wv.x - 2.0f * acc[ti][tj][0], 0.f));
        o.y = sqrtf(fmaxf(xm + wv.y - 2.0f * acc[ti][tj][1], 0.f));
        o.z = sqrtf(fmaxf(xm + wv.z - 2.0f * acc[ti][tj][2], 0.f));
        o.w = sqrtf(fmaxf(xm + wv.w - 2.0f * acc[ti][tj][3], 0.f));
        *(float4*)&orow[nb] = o;
      }
    }
  }
}

// ---------------- fallback path (ws too small): round-1 kernels ----------------
#define LDA 72
#define BKF 64
#define BMF 128
#define BNF 128
__global__ void row_sq_norm(const float* __restrict__ in, float* __restrict__ out,
                            int nrows, int nvalid) {
  int row  = blockIdx.x * 4 + (threadIdx.x >> 6);
  int lane = threadIdx.x & 63;
  if (row >= nrows) return;
  float s = 0.f;
  if (row < nvalid) {
    float4 v = ((const float4*)(in + (size_t)row * DIM))[lane];
    s = v.x * v.x + v.y * v.y + v.z * v.z + v.w * v.w;
  }
  for (int off = 32; off > 0; off >>= 1) s += __shfl_down(s, off, 64);
  if (lane == 0) out[row] = s;
}

__global__ __launch_bounds__(256, 2)
void cdist_gemm_f32(const float* __restrict__ X, const float* __restrict__ W,
                    const float* __restrict__ xsq, const float* __restrict__ wsq,
                    float* __restrict__ out) {
  __shared__ __align__(16) unsigned short As[BMF * LDA];
  __shared__ __align__(16) unsigned short Bs2[BNF * LDA];
  const int tid = threadIdx.x, lane = tid & 63, wave = tid >> 6;
  const int m0 = blockIdx.x * BMF, n0 = blockIdx.y * BNF;
  const int wr = wave >> 1, wc = wave & 1;
  float4_ acc[4][4] = {};
  const int s_col4 = tid & 15, s_row0 = tid >> 4;
  for (int kc = 0; kc < DIM; kc += BKF) {
#pragma unroll
    for (int j = 0; j < 8; ++j) {
      int r = s_row0 + 16 * j;
      float4 v = *(const float4*)(X + (size_t)(m0 + r) * DIM + kc + s_col4 * 4);
      *(ushort4*)&As[r * LDA + s_col4 * 4] =
          make_ushort4(f2bf(v.x), f2bf(v.y), f2bf(v.z), f2bf(v.w));
    }
#pragma unroll
    for (int j = 0; j < 8; ++j) {
      int r = s_row0 + 16 * j, n = n0 + r;
      float4 v = make_float4(0.f, 0.f, 0.f, 0.f);
      if (n < NN) v = *(const float4*)(W + (size_t)n * DIM + kc + s_col4 * 4);
      *(ushort4*)&Bs2[r * LDA + s_col4 * 4] =
          make_ushort4(f2bf(v.x), f2bf(v.y), f2bf(v.z), f2bf(v.w));
    }
    __syncthreads();
    const int q = lane >> 4, i = lane & 15;
#pragma unroll
    for (int ks = 0; ks < BKF; ks += 32) {
      short8 a[4], b[4];
#pragma unroll
      for (int t = 0; t < 4; ++t) {
        a[t] = *(const short8*)&As[(wr * 64 + t * 16 + i) * LDA + ks + q * 8];
        b[t] = *(const short8*)&Bs2[(wc * 64 + t * 16 + i) * LDA + ks + q * 8];
      }
#pragma unroll
      for (int ti = 0; ti < 4; ++ti)
#pragma unroll
        for (int tj = 0; tj < 4; ++tj)
          acc[ti][tj] = __builtin_amdgcn_mfma_f32_16x16x32_bf16(
              a[ti], b[tj], acc[ti][tj], 0, 0, 0);
    }
    __syncthreads();
  }
  const int q = lane >> 4, i = lane & 15;
#pragma unroll
  for (int ti = 0; ti < 4; ++ti) {
    int grow_base = m0 + wr * 64 + ti * 16 + q * 4;
#pragma unroll
    for (int tj = 0; tj < 4; ++tj) {
      int gcol = n0 + wc * 64 + tj * 16 + i;
      if (gcol < NN) {
        float wn = wsq[gcol];
#pragma unroll
        for (int r = 0; r < 4; ++r) {
          int grow = grow_base + r;
          float d2 = xsq[grow] + wn - 2.0f * acc[ti][tj][r];
          out[(size_t)grow * NN + gcol] = sqrtf(fmaxf(d2, 0.f));
        }
      }
    }
  }
}

extern "C" void kernel_launch(void* const* d_in, const int* in_sizes, int n_in,
                              void* d_out, int out_size, void* d_ws, size_t ws_size,
                              hipStream_t stream) {
  const float* x = (const float*)d_in[0];
  const float* w = (const float*)d_in[1];

  const size_t xb_elems = (size_t)BATCH * DIM;          // bf16
  const size_t wb_elems = (size_t)NPAD * DIM;           // bf16
  const size_t need = xb_elems * 2 + wb_elems * 2 + (size_t)BATCH * 4 + (size_t)NPAD * 4;

  if (ws_size >= need) {
    unsigned short* Xb = (unsigned short*)d_ws;
    unsigned short* Wb = Xb + xb_elems;
    float* xsq = (float*)(Wb + wb_elems);
    float* wsq = xsq + BATCH;

    prep_rows2<<<(BATCH + NPAD) / 4, 256, 0, stream>>>(x, w, Xb, xsq);

    cdist_gemm_bf16<<<dim3((BATCH / BM) * (NPAD / BN)), 512, 0, stream>>>(
        Xb, Wb, xsq, wsq, (float*)d_out);
  } else {
    float* xsq = (float*)d_ws;
    float* wsq = xsq + BATCH;
    row_sq_norm<<<BATCH / 4, 256, 0, stream>>>(x, xsq, BATCH, BATCH);
    row_sq_norm<<<NPAD / 4, 256, 0, stream>>>(w, wsq, NPAD, NN);
    dim3 grid(BATCH / BMF, NPAD / BNF);
    cdist_gemm_f32<<<grid, 256, 0, stream>>>(x, w, xsq, wsq, (float*)d_out);
  }
}